// Round 7
// baseline (860.627 us; speedup 1.0000x reference)
//
#include <hip/hip_runtime.h>
#include <hip/hip_bf16.h>
#include <math.h>

// Problem constants (fixed by setup_inputs)
#define BB 128
#define DD 512
#define HH 1024
#define NB 32     // num_coeff_per_dim
#define MM 63     // 2N-1 simpson points
#define TT 16
#define ITERS 10
#define HC 128    // h-chunk
#define NCH (HH / HC)

// ws layout (float units)
#define OFF_U       0        // 32 fp32
#define OFF_TTRUE   64       // 64 fp32 (tt[63]=0)
#define OFF_PHIOUT  128      // 512 fp32
#define OFF_PHIF_BF 1024     // bf16 [64 m][32 n]  (row 63 = 0)   = 1024 floats
#define OFF_QT_BF   2048     // bf16 [32 j][64 m]  (col 63 = 0)   = 1024 floats
#define HDRF        4096
#define OFF_BN      HDRF                     // fp32 [B][512][32]  = 2097152
#define OFF_W1T     (OFF_BN + 2097152)       // bf16 [1024][512]   = 262144 f
#define OFF_W2T     (OFF_W1T + 262144)       // bf16 [512][1024]   = 262144 f
// end = 2625536 floats = 10.5 MB

typedef __attribute__((ext_vector_type(8))) short bf16x8;
typedef __attribute__((ext_vector_type(4))) float f32x4;

static __device__ __forceinline__ unsigned short f2bf(float f) {
    unsigned int x = __builtin_bit_cast(unsigned int, f);
    unsigned int r = x + 0x7FFFu + ((x >> 16) & 1u);   // RNE
    return (unsigned short)(r >> 16);
}

static __device__ __forceinline__ void store4bf(unsigned short* p,
                                                float v0, float v1, float v2, float v3) {
    unsigned int lo = (unsigned int)f2bf(v0) | ((unsigned int)f2bf(v1) << 16);
    unsigned int hi = (unsigned int)f2bf(v2) | ((unsigned int)f2bf(v3) << 16);
    uint2 u; u.x = lo; u.y = hi;
    *(uint2*)p = u;   // 8B-aligned by construction
}

static __device__ __forceinline__ float tanh_fast(float x) {
    float e = exp2f(x * 2.88539008177793f);   // 2*log2(e)
    return 1.0f - 2.0f / (e + 1.0f);
}

// XOR-swizzled Bc tile: [32 r][512 c] bf16, byte=(r<<10 | c*2) ^ ((r&7)<<4).
// Bijective per row (XOR bits 4..6), 16B alignment kept for b128 reads.
static __device__ __forceinline__ unsigned short* aS(unsigned short* smA, int r, int c16) {
    return (unsigned short*)((char*)smA + (((r << 10) + (c16 << 4)) ^ ((r & 7) << 4)));
}

// ---------------------------------------------------------------------------
// Setup: t grids, Phi_f, Phi_inv (double GJ, wave-parallel), Q = R@Phi_inv,
// u, Phi_out, bf16 tables.
// ---------------------------------------------------------------------------
__global__ __launch_bounds__(256) void setup_kernel(const float* __restrict__ t_span,
                                                    float* __restrict__ ws) {
    __shared__ double tsim[MM];
    __shared__ double ttrue_d[MM];
    __shared__ double wid[31];
    __shared__ double phid[NB * MM];   // [n][m]
    __shared__ double aug[NB * 64];    // [Phi | I]
    __shared__ double mlt[NB];
    __shared__ double Rl[MM * NB];
    __shared__ double Qd[MM * NB];     // [m][j]
    __shared__ int    piv_s;

    const int t    = threadIdx.x;  // 256 threads
    const int lane = t & 63;
    const int rgrp = t >> 6;
    const double PI = 3.14159265358979323846;
    const double t0 = (double)t_span[0];
    const double t1 = (double)t_span[TT - 1];

    if (t < MM) {
        double v;
        if ((t & 1) == 0) {
            int j = t >> 1;
            v = -cos(PI * (double)j / (double)(NB - 1));
        } else {
            int i = t >> 1;
            double a = -cos(PI * (double)i / (double)(NB - 1));
            double b = -cos(PI * (double)(i + 1) / (double)(NB - 1));
            v = 0.5 * (a + b);
        }
        tsim[t] = v;
        ttrue_d[t] = t0 + 0.5 * (t1 - t0) * (v + 1.0);
    }
    __syncthreads();
    if (t < 31) wid[t] = (ttrue_d[2 * t + 2] - ttrue_d[2 * t]) / 6.0;
    if (t < MM) ws[OFF_TTRUE + t] = (float)ttrue_d[t];
    if (t == 63) ws[OFF_TTRUE + 63] = 0.0f;

    if (t < MM) {
        double x = tsim[t];
        double r0 = 1.0, r1 = x;
        phid[0 * MM + t] = r0;
        phid[1 * MM + t] = r1;
        for (int n = 2; n < NB; n++) {
            double r2 = 2.0 * x * r1 - r0;
            phid[n * MM + t] = r2;
            r0 = r1; r1 = r2;
        }
    }
    __syncthreads();

    {   // phif_bf [m 64][n 32], row 63 = 0
        unsigned short* pf = (unsigned short*)(ws + OFF_PHIF_BF);
        for (int f = t; f < 64 * 32; f += 256) {
            int m = f >> 5, n = f & 31;
            pf[f] = f2bf(m < MM ? (float)phid[n * MM + m] : 0.0f);
        }
    }

    for (int f = t; f < NB * 64; f += 256) {
        int r = f >> 6, c = f & 63;
        double v;
        if (c < NB) v = phid[r * MM + 2 * c];
        else        v = ((c - NB) == r) ? 1.0 : 0.0;
        aug[f] = v;
    }
    __syncthreads();

    for (int k = 0; k < NB; k++) {
        if (t < 32) {
            double v = (t >= k) ? fabs(aug[t * 64 + k]) : -1.0;
            int idx = t;
            #pragma unroll
            for (int off = 16; off >= 1; off >>= 1) {
                double ov = __shfl_xor(v, off);
                int    oi = __shfl_xor(idx, off);
                if (ov > v) { v = ov; idx = oi; }
            }
            if (t == 0) piv_s = idx;
        }
        __syncthreads();
        const int p = piv_s;
        if (t < 64) {
            double pv   = aug[p * 64 + k];
            double rowp = aug[p * 64 + t];
            double rowk = aug[k * 64 + t];
            aug[k * 64 + t] = rowp / pv;
            if (p != k) aug[p * 64 + t] = rowk;
        }
        __syncthreads();
        if (t < 32) mlt[t] = (t == k) ? 0.0 : aug[t * 64 + k];
        __syncthreads();
        {
            double pk = aug[k * 64 + lane];
            #pragma unroll
            for (int i = 0; i < 8; i++) {
                int r = rgrp * 8 + i;
                aug[r * 64 + lane] -= mlt[r] * pk;
            }
        }
        __syncthreads();
    }

    if (t < MM) {
        double acc = 0.0;
        Rl[t * NB + 0] = 0.0;
        for (int i = 1; i < NB; i++) {
            int ip = i - 1;
            double w = 0.0;
            if (t == 2 * ip)     w += wid[ip];
            if (t == 2 * ip + 1) w += 4.0 * wid[ip];
            if (t == 2 * ip + 2) w += wid[ip];
            acc += w;
            Rl[t * NB + i] = acc;
        }
    }
    __syncthreads();

    for (int f = t; f < MM * NB; f += 256) {
        int m = f >> 5, j = f & 31;
        double s = 0.0;
        for (int i = 0; i < NB; i++) s += Rl[m * NB + i] * aug[i * 64 + 32 + j];
        Qd[f] = s;
    }
    __syncthreads();

    {   // qt_bf [j 32][m 64], col 63 = 0
        unsigned short* qt = (unsigned short*)(ws + OFF_QT_BF);
        for (int f = t; f < 32 * 64; f += 256) {
            int j = f >> 6, m = f & 63;
            qt[f] = f2bf(m < MM ? (float)Qd[m * NB + j] : 0.0f);
        }
    }
    if (t < NB) {
        double s = 0.0;
        for (int i = 0; i < NB; i++) s += aug[i * 64 + 32 + t];
        ws[OFF_U + t] = (float)s;
    }
    if (t < TT) {
        double x = -1.0 + 2.0 * ((double)t_span[t] - t0) / (t1 - t0);
        double r0 = 1.0, r1 = x;
        ws[OFF_PHIOUT + 0 * TT + t] = 1.0f;
        ws[OFF_PHIOUT + 1 * TT + t] = (float)x;
        for (int n = 2; n < NB; n++) {
            double r2 = 2.0 * x * r1 - r0;
            ws[OFF_PHIOUT + n * TT + t] = (float)r2;
            r0 = r1; r1 = r2;
        }
    }
}

// ---------------------------------------------------------------------------
// Transpose fp32 (R x C) -> bf16 (C x R)
// ---------------------------------------------------------------------------
__global__ __launch_bounds__(256) void transpose_f32_bf16(
        const float* __restrict__ in, unsigned short* __restrict__ out,
        int R, int C) {
    __shared__ float tile[32][33];
    const int t = threadIdx.x;
    const int tc = blockIdx.x, tr = blockIdx.y;
    const int c = tc * 32 + (t & 31);
    #pragma unroll
    for (int i = 0; i < 4; i++) {
        int rl = (t >> 5) + i * 8;
        tile[rl][t & 31] = in[(size_t)(tr * 32 + rl) * C + c];
    }
    __syncthreads();
    #pragma unroll
    for (int i = 0; i < 4; i++) {
        int orl = (t >> 5) + i * 8;            // local col of input
        int orow = tc * 32 + orl;
        int ocol = tr * 32 + (t & 31);
        out[(size_t)orow * R + ocol] = f2bf(tile[t & 31][orl]);
    }
}

// ---------------------------------------------------------------------------
// iter_kernel: ONE persistent block per batch element b; the full 10-iteration
// loop runs in-kernel with NO grid sync (b's are independent). Bc lives in LDS
// for the whole solve; h processed in 8 chunks of 128 (16 h per wave ->
// G/Z/tanh/P phases are wave-private, barrier only around shared P-chunk for
// the k2 contraction). Global in-loop traffic: W1t/W2t L2 streams only.
// LDS: bc 32K + gp 10K + tp 18K + pc 8K = 69632 B. 512 thr (8 waves).
// MFMA chains per output element are op-identical to the split-kernel version
// -> bitwise-same results.
// ---------------------------------------------------------------------------
__global__ __launch_bounds__(512) void iter_kernel(
        const float* __restrict__ B_init,        // [B][512 d][32 n] fp32
        const unsigned short* __restrict__ W1t,  // [1024 h][512 d] bf16
        const unsigned short* __restrict__ W2t,  // [512 d][1024 h] bf16
        const float* __restrict__ b1,            // [1024]
        const float* __restrict__ y_init,        // [B][512]
        const float* __restrict__ ws,
        float* __restrict__ Bn)                  // [B][512][32] fp32 (final)
{
    __shared__ __align__(16) char smem[69632];
    unsigned short* bc = (unsigned short*)smem;                        // [32 n][512 d] swz
    const int t    = threadIdx.x;
    const int lane = t & 63;
    const int w    = t >> 6;        // wave 0..7
    const int q    = lane >> 4;
    const int l15  = lane & 15;
    const int b    = blockIdx.x;
    unsigned short* gp = (unsigned short*)(smem + 32768 + w * 1280);   // [16 h][40 n] wave-priv
    unsigned short* tp = (unsigned short*)(smem + 43008 + w * 2304);   // [16 h][72 m] wave-priv
    char*           pc = smem + 61440;                                 // [32 j][128 h] swz shared

    const unsigned short* PF = (const unsigned short*)(ws + OFF_PHIF_BF);
    const unsigned short* QT = (const unsigned short*)(ws + OFF_QT_BF);
    const float* TTp = ws + OFF_TTRUE;
    const float* U   = ws + OFF_U;

    // ---- init Bc = bf16(B_init[b]^T): [512 d][32 n] fp32 -> [n][d] swz ----
    {
        const float* Bi = B_init + (size_t)b * DD * NB;
        #pragma unroll
        for (int i = 0; i < 32; i++) {
            int f = i * 512 + t;                  // coalesced fp32 read
            int d = f >> 5, n = f & 31;
            *(unsigned short*)(smem + (((n << 10) + (d << 1)) ^ ((n & 7) << 4)))
                = f2bf(Bi[f]);
        }
    }
    __syncthreads();

    const int dwv = w * 64;       // wave's d-slice for the k2 accumulator
    float yv[4];
    float4 uv[2];
    #pragma unroll
    for (int nt = 0; nt < 4; nt++)
        yv[nt] = y_init[(size_t)b * DD + dwv + nt * 16 + l15];
    uv[0] = *(const float4*)(U + q * 4);
    uv[1] = *(const float4*)(U + 16 + q * 4);

    #pragma unroll 1
    for (int it = 0; it < ITERS; ++it) {
        const bool last = (it == ITERS - 1);
        f32x4 acc2[2][4] = {};    // [j-tile][d-tile] persistent over chunks

        #pragma unroll 1
        for (int c = 0; c < NCH; ++c) {
            const int hb = c * HC + w * 16;      // wave's 16-h slice

            // ---- G = Bc^T W1 : M=32 n x N=16 h x K=512 (wave-private) ----
            f32x4 ag[2] = {};
            const unsigned short* W1r = W1t + (size_t)(hb + l15) * DD;
            #pragma unroll 4
            for (int d0 = 0; d0 < DD; d0 += 32) {
                int c16 = (d0 >> 3) + q;
                bf16x8 a0 = *(const bf16x8*)aS(bc, l15, c16);
                bf16x8 a1 = *(const bf16x8*)aS(bc, 16 + l15, c16);
                bf16x8 bb = *(const bf16x8*)(W1r + d0 + q * 8);
                ag[0] = __builtin_amdgcn_mfma_f32_16x16x32_bf16(a0, bb, ag[0], 0, 0, 0);
                ag[1] = __builtin_amdgcn_mfma_f32_16x16x32_bf16(a1, bb, ag[1], 0, 0, 0);
            }
            #pragma unroll
            for (int mt = 0; mt < 2; mt++)   // C: col h=l15, row n=mt*16+q*4+r
                store4bf(&gp[l15 * 40 + mt * 16 + q * 4],
                         ag[mt][0], ag[mt][1], ag[mt][2], ag[mt][3]);

            // ---- Z = Phi_f^T G : M=64 m x N=16 h x K=32 n ----
            f32x4 z[4] = {};
            bf16x8 gb = *(const bf16x8*)(&gp[l15 * 40 + q * 8]);
            #pragma unroll
            for (int mt = 0; mt < 4; mt++) {
                bf16x8 af = *(const bf16x8*)(PF + (mt * 16 + l15) * 32 + q * 8);
                z[mt] = __builtin_amdgcn_mfma_f32_16x16x32_bf16(af, gb, z[mt], 0, 0, 0);
            }

            // ---- T = tanh(Z + t_true*b1), layout [h][m] wave-private ----
            float b1v = b1[hb + l15];
            #pragma unroll
            for (int mt = 0; mt < 4; mt++) {
                float4 ttv = *(const float4*)(TTp + mt * 16 + q * 4);
                float v0 = tanh_fast(z[mt][0] + ttv.x * b1v);
                float v1 = tanh_fast(z[mt][1] + ttv.y * b1v);
                float v2 = tanh_fast(z[mt][2] + ttv.z * b1v);
                float v3 = tanh_fast(z[mt][3] + ttv.w * b1v);
                store4bf(&tp[l15 * 72 + mt * 16 + q * 4], v0, v1, v2, v3);
            }

            // ---- P = Q^T T : M=32 j x N=16 h x K=64 m ----
            f32x4 p[2] = {};
            #pragma unroll
            for (int ks = 0; ks < 2; ks++) {
                bf16x8 bt = *(const bf16x8*)(&tp[l15 * 72 + ks * 32 + q * 8]);
                #pragma unroll
                for (int jt = 0; jt < 2; jt++) {
                    bf16x8 aq = *(const bf16x8*)(QT + (jt * 16 + l15) * 64 + ks * 32 + q * 8);
                    p[jt] = __builtin_amdgcn_mfma_f32_16x16x32_bf16(aq, bt, p[jt], 0, 0, 0);
                }
            }
            {   // write P chunk [j][h] swz; h-col = w*16 + l15
                int hcol = w * 16 + l15;
                #pragma unroll
                for (int jt = 0; jt < 2; jt++)
                    #pragma unroll
                    for (int r = 0; r < 4; r++) {
                        int j = jt * 16 + q * 4 + r;
                        *(unsigned short*)(pc + ((j << 8) + ((hcol << 1) ^ ((j & 7) << 4))))
                            = f2bf(p[jt][r]);
                    }
            }
            __syncthreads();   // P chunk visible to all waves

            // ---- k2 partial: acc2 += P W2 : M=32 j x N=64 d x K=128 h ----
            #pragma unroll
            for (int ks = 0; ks < 4; ks++) {
                int kb = (ks << 6) + (q << 4);
                bf16x8 a0 = *(const bf16x8*)(pc + ((l15 << 8) + (kb ^ ((l15 & 7) << 4))));
                bf16x8 a1 = *(const bf16x8*)(pc + (((16 + l15) << 8) + (kb ^ ((l15 & 7) << 4))));
                #pragma unroll
                for (int nt = 0; nt < 4; nt++) {
                    bf16x8 bb = *(const bf16x8*)(W2t + (size_t)(dwv + nt * 16 + l15) * HH
                                                 + c * HC + ks * 32 + q * 8);
                    acc2[0][nt] = __builtin_amdgcn_mfma_f32_16x16x32_bf16(a0, bb, acc2[0][nt], 0, 0, 0);
                    acc2[1][nt] = __builtin_amdgcn_mfma_f32_16x16x32_bf16(a1, bb, acc2[1][nt], 0, 0, 0);
                }
            }
            __syncthreads();   // all P reads done before next chunk overwrites
        }

        // ---- iteration epilogue: val = acc + y*u; update Bc (or write Bn) ----
        #pragma unroll
        for (int mt = 0; mt < 2; mt++) {
            #pragma unroll
            for (int nt = 0; nt < 4; nt++) {
                int d = dwv + nt * 16 + l15;
                #pragma unroll
                for (int r = 0; r < 4; r++) {
                    int j = mt * 16 + q * 4 + r;
                    float uvr = (r == 0) ? uv[mt].x : (r == 1) ? uv[mt].y
                              : (r == 2) ? uv[mt].z : uv[mt].w;
                    float val = acc2[mt][nt][r] + yv[nt] * uvr;
                    if (!last)
                        *(unsigned short*)(smem + (((j << 10) + (d << 1)) ^ ((j & 7) << 4)))
                            = f2bf(val);
                    else
                        Bn[((size_t)b * DD + d) * NB + j] = val;
                }
            }
        }
        __syncthreads();   // Bc consistent before next iteration's G phase
    }
}

// ---------------------------------------------------------------------------
// K3: out0[t,b,d] = sum_n Bn[b,d,n]*Phi_out[n,t] ; out1 = Bn
// ---------------------------------------------------------------------------
__global__ __launch_bounds__(256) void k3_kernel(
        const float* __restrict__ ws_c, float* __restrict__ out) {
    __shared__ float rows_s[64 * 33];
    __shared__ float phiout_s[NB * TT];

    const int t = threadIdx.x;
    const int r0 = blockIdx.x * 64;
    const float* Bf = ws_c + OFF_BN;

    for (int f = t; f < NB * TT; f += 256) phiout_s[f] = ws_c[OFF_PHIOUT + f];

    float vals[8];
    {
        int f = t;
        #pragma unroll
        for (int i = 0; i < 8; i++, f += 256) {
            float v = Bf[(size_t)r0 * NB + f];
            rows_s[(f >> 5) * 33 + (f & 31)] = v;
            vals[i] = v;
        }
    }
    float* out1 = out + (size_t)TT * BB * DD;
    {
        int f = t;
        #pragma unroll
        for (int i = 0; i < 8; i++, f += 256) out1[(size_t)r0 * NB + f] = vals[i];
    }
    __syncthreads();

    #pragma unroll
    for (int i = 0; i < 4; i++) {
        int idx = i * 256 + t;
        int tt = idx >> 6, rl = idx & 63;
        float s = 0.f;
        #pragma unroll
        for (int n = 0; n < NB; n++)
            s += rows_s[rl * 33 + n] * phiout_s[n * TT + tt];
        out[(size_t)tt * (BB * DD) + r0 + rl] = s;
    }
}

// ---------------------------------------------------------------------------
extern "C" void kernel_launch(void* const* d_in, const int* in_sizes, int n_in,
                              void* d_out, int out_size, void* d_ws, size_t ws_size,
                              hipStream_t stream) {
    const float* t_span = (const float*)d_in[0];
    const float* y_init = (const float*)d_in[1];
    const float* B_init = (const float*)d_in[2];
    const float* W1     = (const float*)d_in[3];
    const float* b1     = (const float*)d_in[4];
    const float* W2     = (const float*)d_in[5];
    float* ws  = (float*)d_ws;
    float* out = (float*)d_out;

    unsigned short* W1t = (unsigned short*)(ws + OFF_W1T);
    unsigned short* W2t = (unsigned short*)(ws + OFF_W2T);
    float*          Bn  = ws + OFF_BN;

    setup_kernel<<<1, 256, 0, stream>>>(t_span, ws);
    transpose_f32_bf16<<<dim3(HH / 32, DD / 32), 256, 0, stream>>>(W1, W1t, DD, HH);
    transpose_f32_bf16<<<dim3(DD / 32, HH / 32), 256, 0, stream>>>(W2, W2t, HH, DD);

    iter_kernel<<<dim3(BB), dim3(512), 0, stream>>>(B_init, W1t, W2t, b1, y_init, ws, Bn);

    k3_kernel<<<dim3((BB * DD) / 64), 256, 0, stream>>>(ws, out);
}